// Round 19
// baseline (44.857 us; speedup 1.0000x reference)
//
#include <hip/hip_runtime.h>

typedef _Float16 half8  __attribute__((ext_vector_type(8)));
typedef __fp16   fp16x2 __attribute__((ext_vector_type(2)));
typedef float    float4_t __attribute__((ext_vector_type(4)));

#define SH 4
#define SW 160
#define CW (SW + 2)   // 162 staged cv cols
#define NR (SH + 2)   // 6 staged rows
#define DW (CW + 1)   // 163: depth LDS row stride

// VALU-pipe rotate-reduce within each 16-lane row: v += dpp_ror<N>(v)
template <int CTRL>
__device__ __forceinline__ float rr_add(float v) {
    const int i = __float_as_int(v);
    const int p = __builtin_amdgcn_update_dpp(i, i, CTRL, 0xF, 0xF, false);
    return v + __int_as_float(p);
}
#define ROR4 0x124
#define ROR8 0x128

__global__ __launch_bounds__(256, 4) void depth_up_fused(
    const float* __restrict__ depth,
    const float* __restrict__ cv,
    const float* __restrict__ w1,   // [8,8,3,3]
    const float* __restrict__ b1,   // [8]
    const float* __restrict__ w2,   // [36,8]
    const float* __restrict__ b2,   // [36]
    float* __restrict__ out)        // [N, 1024, 1280]
{
    const int H = 512, W = 640;
    const size_t HW = (size_t)H * W;
    const int n  = blockIdx.z;
    const int h0 = blockIdx.y * SH;
    const int cb = blockIdx.x * SW;
    const int tid  = threadIdx.x;
    const int lane = tid & 63;
    const int wv   = tid >> 6;       // wave = row within strip
    const int o    = lane & 15;
    const int krow = lane >> 4;
    const int u    = o >> 2;         // tap-group
    const int q    = o & 3;          // softmax column

    __shared__ half8 s_cv[NR * CW];  // 15,552 B
    __shared__ float s_d[NR * DW];   //  3,912 B

    const float* __restrict__ cvn = cv + (size_t)n * 8 * HW;
    const float* __restrict__ dn  = depth + (size_t)n * HW;

    // ---- stage cv (fp16x8) + depth: branchless, 972 items padded to 1024 ----
    #pragma unroll
    for (int j = 0; j < 4; ++j) {
        const int i0 = tid + 256 * j;
        const int it = i0 < (NR * CW - 1) ? i0 : (NR * CW - 1);
        const int r  = it / CW;
        const int c  = it - r * CW;
        const int gh = h0 + r - 1;
        const int gw = cb + c - 1;
        const int ghs = gh < 0 ? 0 : (gh > H - 1 ? H - 1 : gh);
        const int gws = gw < 0 ? 0 : (gw > W - 1 ? W - 1 : gw);
        const bool ok = (gh == ghs) & (gw == gws);
        const float* p = cvn + (size_t)ghs * W + gws;
        float f[9];
        #pragma unroll
        for (int ch = 0; ch < 8; ++ch) f[ch] = p[(size_t)ch * HW];
        f[8] = dn[(size_t)ghs * W + gws];
        #pragma unroll
        for (int k = 0; k < 9; ++k) f[k] = ok ? f[k] : 0.0f;
        union { half8 v8; fp16x2 h2[4]; } hu;
        #pragma unroll
        for (int pq = 0; pq < 4; ++pq)
            hu.h2[pq] = __builtin_amdgcn_cvt_pkrtz(f[2 * pq], f[2 * pq + 1]);
        s_cv[r * CW + c] = hu.v8;
        s_d[r * DW + c]  = f[8];
    }

    // ---- conv1 weights as A-fragments: A1[row=och][k], k = tap*8 + c ----
    half8 a1[3];
    #pragma unroll
    for (int ki = 0; ki < 3; ++ki) {
        const int tap = 4 * ki + krow;
        #pragma unroll
        for (int j = 0; j < 8; ++j)
            a1[ki][j] = (tap < 9 && o < 8) ? (_Float16)w1[(o * 8 + j) * 9 + tap]
                                           : (_Float16)0.0f;
    }
    int aoff[3];
    #pragma unroll
    for (int ki = 0; ki < 3; ++ki) {
        const int tap0 = 4 * ki + krow;
        const int tap  = tap0 > 8 ? 8 : tap0;
        const int ky   = tap / 3;
        const int kx   = tap - 3 * ky;
        aoff[ki] = ((wv + ky) * CW + o + kx) * 16;
    }
    const float4_t b1q = *reinterpret_cast<const float4_t*>(b1 + (krow & 1) * 4);

    half8 b2f[3] = {};
    if (krow == 0) {
        #pragma unroll
        for (int t = 0; t < 3; ++t) {
            const int m = (o + 16 * t) > 35 ? 35 : (o + 16 * t);
            const float4_t wlo = *reinterpret_cast<const float4_t*>(w2 + m * 8);
            const float4_t whi = *reinterpret_cast<const float4_t*>(w2 + m * 8 + 4);
            #pragma unroll
            for (int j = 0; j < 4; ++j) {
                b2f[t][j]     = (_Float16)wlo[j];
                b2f[t][4 + j] = (_Float16)whi[j];
            }
        }
    }
    const float C = 0.25f * 1.44269504f;
    float b2q[3];
    #pragma unroll
    for (int t = 0; t < 3; ++t) {
        const int m = (o + 16 * t) > 35 ? 35 : (o + 16 * t);
        b2q[t] = C * b2[m];
    }
    if (u != 0) b2q[2] = -1.0e38f;   // exp2 -> 0 for the invalid tap

    int poff[3];
    {
        const int taps[3] = {u, u + 4, 8};
        #pragma unroll
        for (int t = 0; t < 3; ++t) {
            const int ky = taps[t] / 3;
            const int kx = taps[t] - 3 * ky;
            poff[t] = ((wv + ky) * DW + kx) * 4;
        }
    }

    __syncthreads();

    const char* cvb = (const char*)s_cv;
    const char* sdb = (const char*)s_d;
    const float4_t zero4 = {0.0f, 0.0f, 0.0f, 0.0f};

    const half8* bb0 = (const half8*)(cvb + aoff[0]);
    const half8* bb1 = (const half8*)(cvb + aoff[1]);
    const half8* bb2 = (const half8*)(cvb + aoff[2]);
    const float* pb0 = (const float*)(sdb + poff[0] + krow * 16);
    const float* pb1 = (const float*)(sdb + poff[1] + krow * 16);
    const float* pb2 = (const float*)(sdb + poff[2] + krow * 16);
    float* ob = out + ((size_t)n * 1024 + (size_t)(2 * (h0 + wv) + (q >> 1))) * 1280
                    + (size_t)(2 * (cb + 4 * krow + u) + (q & 1));

    // ---- 5 trips; streams A (pp) and B (pp+5) HAND-INTERLEAVED stage-by-stage
    for (int pp = 0; pp < 5; ++pp) {
        const int psA = pp, psB = pp + 5;

        // stage 0: issue ALL LDS loads for both streams (6 x ds_read_b128)
        const half8 cA0 = bb0[psA * 16];
        const half8 cB0 = bb0[psB * 16];
        const half8 cA1 = bb1[psA * 16];
        const half8 cB1 = bb1[psB * 16];
        const half8 cA2 = bb2[psA * 16];
        const half8 cB2 = bb2[psB * 16];

        // stage 1: conv1, A/B alternated
        float4_t accA = zero4, accB = zero4;
        accA = __builtin_amdgcn_mfma_f32_16x16x32_f16(a1[0], cA0, accA, 0, 0, 0);
        accB = __builtin_amdgcn_mfma_f32_16x16x32_f16(a1[0], cB0, accB, 0, 0, 0);
        accA = __builtin_amdgcn_mfma_f32_16x16x32_f16(a1[1], cA1, accA, 0, 0, 0);
        accB = __builtin_amdgcn_mfma_f32_16x16x32_f16(a1[1], cB1, accB, 0, 0, 0);
        accA = __builtin_amdgcn_mfma_f32_16x16x32_f16(a1[2], cA2, accA, 0, 0, 0);
        accB = __builtin_amdgcn_mfma_f32_16x16x32_f16(a1[2], cB2, accB, 0, 0, 0);

        // stage 2: relu+pack, A/B alternated
        union { half8 v; fp16x2 h2[4]; uint32_t u32[4]; } a2A, a2B;
        a2A.h2[0] = __builtin_amdgcn_cvt_pkrtz(fmaxf(accA[0] + b1q[0], 0.0f),
                                               fmaxf(accA[1] + b1q[1], 0.0f));
        a2B.h2[0] = __builtin_amdgcn_cvt_pkrtz(fmaxf(accB[0] + b1q[0], 0.0f),
                                               fmaxf(accB[1] + b1q[1], 0.0f));
        a2A.h2[1] = __builtin_amdgcn_cvt_pkrtz(fmaxf(accA[2] + b1q[2], 0.0f),
                                               fmaxf(accA[3] + b1q[3], 0.0f));
        a2B.h2[1] = __builtin_amdgcn_cvt_pkrtz(fmaxf(accB[2] + b1q[2], 0.0f),
                                               fmaxf(accB[3] + b1q[3], 0.0f));

        // stage 3: xor16 exchanges, A/B alternated (4 ds_bpermute in flight)
        a2A.u32[2] = (uint32_t)__shfl_xor((int)a2A.u32[0], 16);
        a2B.u32[2] = (uint32_t)__shfl_xor((int)a2B.u32[0], 16);
        a2A.u32[3] = (uint32_t)__shfl_xor((int)a2A.u32[1], 16);
        a2B.u32[3] = (uint32_t)__shfl_xor((int)a2B.u32[1], 16);

        // stage 4: conv2, A/B alternated
        const float4_t dA0 = __builtin_amdgcn_mfma_f32_16x16x32_f16(a2A.v, b2f[0], zero4, 0, 0, 0);
        const float4_t dB0 = __builtin_amdgcn_mfma_f32_16x16x32_f16(a2B.v, b2f[0], zero4, 0, 0, 0);
        const float4_t dA1 = __builtin_amdgcn_mfma_f32_16x16x32_f16(a2A.v, b2f[1], zero4, 0, 0, 0);
        const float4_t dB1 = __builtin_amdgcn_mfma_f32_16x16x32_f16(a2B.v, b2f[1], zero4, 0, 0, 0);
        const float4_t dA2 = __builtin_amdgcn_mfma_f32_16x16x32_f16(a2A.v, b2f[2], zero4, 0, 0, 0);
        const float4_t dB2 = __builtin_amdgcn_mfma_f32_16x16x32_f16(a2B.v, b2f[2], zero4, 0, 0, 0);

        // stage 5: softmax exps + weighted sums, A/B alternated per r
        float seA[4], spA[4], seB[4], spB[4];
        #pragma unroll
        for (int r = 0; r < 4; ++r) {
            const float eA0 = __builtin_amdgcn_exp2f(fmaf(dA0[r], C, b2q[0]));
            const float eB0 = __builtin_amdgcn_exp2f(fmaf(dB0[r], C, b2q[0]));
            const float eA1 = __builtin_amdgcn_exp2f(fmaf(dA1[r], C, b2q[1]));
            const float eB1 = __builtin_amdgcn_exp2f(fmaf(dB1[r], C, b2q[1]));
            const float eA2 = __builtin_amdgcn_exp2f(fmaf(dA2[r], C, b2q[2]));
            const float eB2 = __builtin_amdgcn_exp2f(fmaf(dB2[r], C, b2q[2]));
            const float pA0 = pb0[psA * 16 + r], pB0 = pb0[psB * 16 + r];
            const float pA1 = pb1[psA * 16 + r], pB1 = pb1[psB * 16 + r];
            const float pA2 = pb2[psA * 16 + r], pB2 = pb2[psB * 16 + r];
            seA[r] = eA0 + eA1 + eA2;
            seB[r] = eB0 + eB1 + eB2;
            spA[r] = eA0 * pA0 + eA1 * pA1 + eA2 * pA2;
            spB[r] = eB0 * pB0 + eB1 * pB1 + eB2 * pB2;
        }

        // stage 6: DPP reductions, A/B alternated
        #pragma unroll
        for (int r = 0; r < 4; ++r) {
            seA[r] = rr_add<ROR8>(rr_add<ROR4>(seA[r]));
            seB[r] = rr_add<ROR8>(rr_add<ROR4>(seB[r]));
            spA[r] = rr_add<ROR8>(rr_add<ROR4>(spA[r]));
            spB[r] = rr_add<ROR8>(rr_add<ROR4>(spB[r]));
        }

        // stage 7: divides + selects + stores
        float resA[4], resB[4];
        #pragma unroll
        for (int r = 0; r < 4; ++r) {
            resA[r] = spA[r] * __builtin_amdgcn_rcpf(seA[r]);
            resB[r] = spB[r] * __builtin_amdgcn_rcpf(seB[r]);
        }
        const float vA01 = (u & 1) ? resA[1] : resA[0];
        const float vA23 = (u & 1) ? resA[3] : resA[2];
        const float vB01 = (u & 1) ? resB[1] : resB[0];
        const float vB23 = (u & 1) ? resB[3] : resB[2];
        ob[psA * 32] = (u & 2) ? vA23 : vA01;
        ob[psB * 32] = (u & 2) ? vB23 : vB01;
    }
}

extern "C" void kernel_launch(void* const* d_in, const int* in_sizes, int n_in,
                              void* d_out, int out_size, void* d_ws, size_t ws_size,
                              hipStream_t stream) {
    (void)in_sizes; (void)n_in; (void)out_size; (void)d_ws; (void)ws_size;
    const float* depth = (const float*)d_in[0];
    const float* cv    = (const float*)d_in[1];
    const float* w1    = (const float*)d_in[2];
    const float* b1    = (const float*)d_in[3];
    const float* w2    = (const float*)d_in[4];
    const float* b2    = (const float*)d_in[5];
    float* out = (float*)d_out;

    dim3 grid(640 / SW, 512 / SH, 4);   // (4, 128, 4) = 2048 blocks
    dim3 block(256);
    hipLaunchKernelGGL(depth_up_fused, grid, block, 0, stream,
                       depth, cv, w1, b1, w2, b2, out);
}